// Round 3
// baseline (148.755 us; speedup 1.0000x reference)
//
#include <hip/hip_runtime.h>
#include <math.h>

#define BB 8
#define TT 96
#define SS 192
#define DIN 512
#define DM 512

typedef short short8 __attribute__((ext_vector_type(8)));
typedef float f32x4 __attribute__((ext_vector_type(4)));

__device__ __forceinline__ unsigned short f2bf(float f) {
    unsigned int u = __float_as_uint(f);
    unsigned int r = u + 0x7FFFu + ((u >> 16) & 1u);   // RNE
    return (unsigned short)(r >> 16);
}
__device__ __forceinline__ float bf2f(unsigned short h) {
    return __uint_as_float(((unsigned int)h) << 16);
}

// ---------------- bf16 MFMA GEMM tile with inline fp32->bf16 staging -------
// out[m][n] = bias[n] + sum_k A[m][k] * W[n][k],  A = concat(A1[K1], A2) fp32.
// 64x64 tile, 256 thr, BK=64, double-buffered LDS (pad stride 72), loads
// issued one chunk ahead into VGPRs; cvt+ds_write overlaps MFMA.
#define LDPAD 72
#define BUFSZ (64 * LDPAD)

__device__ __forceinline__ void gemm_tile(
    unsigned short* As, unsigned short* Ws,
    const float* __restrict__ A1, const float* __restrict__ A2, int K1,
    const float* __restrict__ W, const float* __restrict__ bias,
    float* __restrict__ outF, unsigned short* __restrict__ outB,
    int bm, int bn, int N, int K)
{
    const int tid = threadIdx.x;
    const int lane = tid & 63, wv = tid >> 6;
    const int quad = lane >> 4, mrow = lane & 15;
    const int K2s = K - K1;

    f32x4 acc[4] = {{0,0,0,0},{0,0,0,0},{0,0,0,0},{0,0,0,0}};
    float4 ra[4], rw[4];

    auto stage_load = [&](int c) {
        const int gk0 = c << 6;
        #pragma unroll
        for (int i = 0; i < 4; ++i) {
            int flat = i * 1024 + tid * 4;
            int row = flat >> 6, k = flat & 63;
            int gk = gk0 + k;
            const float* ap = (gk < K1)
                ? A1 + (size_t)(bm + row) * K1 + gk
                : A2 + (size_t)(bm + row) * K2s + (gk - K1);
            ra[i] = *(const float4*)ap;
            rw[i] = *(const float4*)(W + (size_t)(bn + row) * K + gk);
        }
    };
    auto cvt_store = [&](int buf) {
        unsigned short* Ab = As + buf * BUFSZ;
        unsigned short* Wb = Ws + buf * BUFSZ;
        #pragma unroll
        for (int i = 0; i < 4; ++i) {
            int flat = i * 1024 + tid * 4;
            int row = flat >> 6, k = flat & 63;
            uint2 pa, pw;
            pa.x = (unsigned)f2bf(ra[i].x) | ((unsigned)f2bf(ra[i].y) << 16);
            pa.y = (unsigned)f2bf(ra[i].z) | ((unsigned)f2bf(ra[i].w) << 16);
            pw.x = (unsigned)f2bf(rw[i].x) | ((unsigned)f2bf(rw[i].y) << 16);
            pw.y = (unsigned)f2bf(rw[i].z) | ((unsigned)f2bf(rw[i].w) << 16);
            *(uint2*)(Ab + row * LDPAD + k) = pa;
            *(uint2*)(Wb + row * LDPAD + k) = pw;
        }
    };

    const int NC = K >> 6;
    stage_load(0);
    cvt_store(0);
    if (NC > 1) stage_load(1);
    __syncthreads();

    for (int c = 0; c < NC; ++c) {
        const int cur = c & 1;
        const unsigned short* Ab = As + cur * BUFSZ;
        const unsigned short* Wb = Ws + cur * BUFSZ;
        short8 av[2], bw[2][4];
        #pragma unroll
        for (int s = 0; s < 2; ++s) {
            av[s] = *(const short8*)(Ab + (wv * 16 + mrow) * LDPAD + s * 32 + quad * 8);
            #pragma unroll
            for (int ct = 0; ct < 4; ++ct)
                bw[s][ct] = *(const short8*)(Wb + (ct * 16 + mrow) * LDPAD + s * 32 + quad * 8);
        }
        if (c + 1 < NC) {
            cvt_store(1 - cur);
            if (c + 2 < NC) stage_load(c + 2);
        }
        #pragma unroll
        for (int s = 0; s < 2; ++s)
            #pragma unroll
            for (int ct = 0; ct < 4; ++ct)
                acc[ct] = __builtin_amdgcn_mfma_f32_16x16x32_bf16(av[s], bw[s][ct], acc[ct], 0, 0, 0);
        __syncthreads();
    }

    #pragma unroll
    for (int ct = 0; ct < 4; ++ct) {
        int col = bn + ct * 16 + mrow;
        float bv = bias ? bias[col] : 0.0f;
        #pragma unroll
        for (int rg = 0; rg < 4; ++rg) {
            int rw_ = bm + wv * 16 + quad * 4 + rg;   // C/D: col=lane&15, row=quad*4+reg
            float val = acc[ct][rg] + bv;
            if (outF) outF[(size_t)rw_ * N + col] = val;
            else      outB[(size_t)rw_ * N + col] = f2bf(val);
        }
    }
}

// fused wq + uh projection: blocks [0,96) -> wq (M=768), [96,288) -> uh (M=1536)
__global__ __launch_bounds__(256) void proj_gemm(
    const float* __restrict__ inputs, const float* __restrict__ mems,
    const float* __restrict__ Wq, const float* __restrict__ Wc,
    const float* __restrict__ bc,
    unsigned short* __restrict__ wq_o, unsigned short* __restrict__ uh_o)
{
    __shared__ __align__(16) unsigned short As[2 * BUFSZ];
    __shared__ __align__(16) unsigned short Ws[2 * BUFSZ];
    int bid = blockIdx.x;
    if (bid < 96) {
        gemm_tile(As, Ws, inputs, inputs, DIN, Wq, nullptr, nullptr, wq_o,
                  (bid >> 3) * 64, (bid & 7) * 64, DM, DIN);
    } else {
        bid -= 96;
        gemm_tile(As, Ws, mems, mems, DM, Wc, bc, nullptr, uh_o,
                  (bid >> 3) * 64, (bid & 7) * 64, DM, DM);
    }
}

// attn_h = concat(c, inputs) @ Wout^T + bout   (M=768, N=512, K=1024)
__global__ __launch_bounds__(256) void out_gemm(
    const float* __restrict__ c_ws, const float* __restrict__ inputs,
    const float* __restrict__ Wout, const float* __restrict__ bout,
    float* __restrict__ attn_h)
{
    __shared__ __align__(16) unsigned short As[2 * BUFSZ];
    __shared__ __align__(16) unsigned short Ws[2 * BUFSZ];
    int bid = blockIdx.x;
    gemm_tile(As, Ws, c_ws, inputs, DM, Wout, bout, attn_h, nullptr,
              (bid >> 3) * 64, (bid & 7) * 64, DIN, DM + DIN);
}

// ---------------- fused scores + softmax + context: 2 rows per block -------
__global__ __launch_bounds__(256) void attn_core(
    const unsigned short* __restrict__ wq,     // [B*T][DM] bf16
    const unsigned short* __restrict__ uh,     // [B*S][DM] bf16
    const float* __restrict__ v,               // [DM] fp32
    const float* __restrict__ mems,            // [B*S][DM] fp32
    const int* __restrict__ masks,             // [B]
    float* __restrict__ align_out,             // [B*T][S] fp32
    float* __restrict__ c_out)                 // [B*T][DM] fp32
{
    __shared__ float s_al[2][SS];
    __shared__ float s_inv[2];
    const int r0 = blockIdx.x * 2, b = r0 / TT;
    const int tid = threadIdx.x, lane = tid & 63, wid = tid >> 6;
    const int len = masks[b];

    float q0[8], q1[8], vf[8];
    {
        short8 qa = *(const short8*)(wq + (size_t)r0 * DM + lane * 8);
        short8 qb = *(const short8*)(wq + (size_t)(r0 + 1) * DM + lane * 8);
        float4 v0 = *(const float4*)(v + lane * 8);
        float4 v1 = *(const float4*)(v + lane * 8 + 4);
        #pragma unroll
        for (int j = 0; j < 8; ++j) {
            q0[j] = bf2f((unsigned short)qa[j]);
            q1[j] = bf2f((unsigned short)qb[j]);
        }
        vf[0] = v0.x; vf[1] = v0.y; vf[2] = v0.z; vf[3] = v0.w;
        vf[4] = v1.x; vf[5] = v1.y; vf[6] = v1.z; vf[7] = v1.w;
    }

    for (int s = wid; s < SS; s += 4) {
        float p0 = -INFINITY, p1 = -INFINITY;
        if (s < len) {
            short8 u = *(const short8*)(uh + ((size_t)b * SS + s) * DM + lane * 8);
            float a0 = 0.f, a1 = 0.f;
            #pragma unroll
            for (int j = 0; j < 8; ++j) {
                float uf = bf2f((unsigned short)u[j]);
                float x0 = (q0[j] + uf) * 2.885390082f;   // 2/ln2
                float x1 = (q1[j] + uf) * 2.885390082f;
                float e0 = __builtin_amdgcn_exp2f(x0);
                float e1 = __builtin_amdgcn_exp2f(x1);
                float t0 = fmaf(-2.f, __builtin_amdgcn_rcpf(e0 + 1.f), 1.f);
                float t1 = fmaf(-2.f, __builtin_amdgcn_rcpf(e1 + 1.f), 1.f);
                a0 = fmaf(vf[j], t0, a0);
                a1 = fmaf(vf[j], t1, a1);
            }
            #pragma unroll
            for (int off = 32; off; off >>= 1) {
                a0 += __shfl_xor(a0, off);
                a1 += __shfl_xor(a1, off);
            }
            p0 = a0; p1 = a1;
        }
        if (lane == 0) { s_al[0][s] = p0; s_al[1][s] = p1; }
    }
    __syncthreads();

    if (tid < 128) {
        const int row = tid >> 6, l = tid & 63;
        float* sa = s_al[row];
        float m = fmaxf(fmaxf(sa[l], sa[l + 64]), sa[l + 128]);
        #pragma unroll
        for (int off = 32; off; off >>= 1) m = fmaxf(m, __shfl_xor(m, off));
        float e0 = __builtin_amdgcn_exp2f((sa[l]       - m) * 1.44269504f);
        float e1 = __builtin_amdgcn_exp2f((sa[l + 64]  - m) * 1.44269504f);
        float e2 = __builtin_amdgcn_exp2f((sa[l + 128] - m) * 1.44269504f);
        sa[l] = e0; sa[l + 64] = e1; sa[l + 128] = e2;
        float sum = e0 + e1 + e2;
        #pragma unroll
        for (int off = 32; off; off >>= 1) sum += __shfl_xor(sum, off);
        if (l == 0) s_inv[row] = 1.0f / sum;
    }
    __syncthreads();

    const float inv0 = s_inv[0], inv1 = s_inv[1];
    if (tid < SS)
        align_out[(size_t)r0 * SS + tid] = s_al[0][tid] * inv0;
    if (tid >= 64)
        align_out[(size_t)(r0 + 1) * SS + (tid - 64)] = s_al[1][tid - 64] * inv1;

    // context: thread owns dims 2*tid, 2*tid+1 for both rows, mems read fp32
    const float* mb = mems + (size_t)b * SS * DM;
    const int d0 = tid * 2;
    float a00 = 0.f, a01 = 0.f, a10 = 0.f, a11 = 0.f;
    for (int s = 0; s < len; ++s) {
        float2 mv = *(const float2*)(mb + (size_t)s * DM + d0);
        float p0 = s_al[0][s], p1 = s_al[1][s];
        a00 = fmaf(p0, mv.x, a00); a01 = fmaf(p0, mv.y, a01);
        a10 = fmaf(p1, mv.x, a10); a11 = fmaf(p1, mv.y, a11);
    }
    float2 c0 = { a00 * inv0, a01 * inv0 };
    float2 c1 = { a10 * inv1, a11 * inv1 };
    *(float2*)(c_out + (size_t)r0 * DM + d0) = c0;
    *(float2*)(c_out + (size_t)(r0 + 1) * DM + d0) = c1;
}

extern "C" void kernel_launch(void* const* d_in, const int* in_sizes, int n_in,
                              void* d_out, int out_size, void* d_ws, size_t ws_size,
                              hipStream_t stream) {
    (void)in_sizes; (void)n_in; (void)out_size; (void)ws_size;
    const float* inputs = (const float*)d_in[0];
    const float* mems   = (const float*)d_in[1];
    const int*   masks  = (const int*)  d_in[2];
    const float* Wq     = (const float*)d_in[3];
    const float* Wc     = (const float*)d_in[4];
    const float* bc     = (const float*)d_in[5];
    const float* v      = (const float*)d_in[6];
    const float* Wout   = (const float*)d_in[7];
    const float* bout   = (const float*)d_in[8];

    unsigned short* wq_bf = (unsigned short*)d_ws;            // [768][512] bf16
    unsigned short* uh_bf = wq_bf + (size_t)BB * TT * DM;     // [1536][512] bf16
    float*          c_ws  = (float*)(uh_bf + (size_t)BB * SS * DM);  // [768][512] f32

    float* attn_h    = (float*)d_out;                    // [768][512]
    float* align_out = attn_h + (size_t)BB * TT * DIN;   // [768][192]

    proj_gemm<<<288, 256, 0, stream>>>(inputs, mems, Wq, Wc, bc, wq_bf, uh_bf);
    attn_core<<<(BB * TT) / 2, 256, 0, stream>>>(wq_bf, uh_bf, v, mems, masks,
                                                 align_out, c_ws);
    out_gemm<<<96, 256, 0, stream>>>(c_ws, inputs, Wout, bout, attn_h);
}

// Round 4
// 145.297 us; speedup vs baseline: 1.0238x; 1.0238x over previous
//
#include <hip/hip_runtime.h>
#include <math.h>

#define BB 8
#define TT 96
#define SS 192
#define DIN 512
#define DM 512

typedef short short8 __attribute__((ext_vector_type(8)));
typedef float f32x4 __attribute__((ext_vector_type(4)));

__device__ __forceinline__ unsigned short f2bf(float f) {
    unsigned int u = __float_as_uint(f);
    unsigned int r = u + 0x7FFFu + ((u >> 16) & 1u);   // RNE
    return (unsigned short)(r >> 16);
}
__device__ __forceinline__ float bf2f(unsigned short h) {
    return __uint_as_float(((unsigned int)h) << 16);
}

// ---------------- prep: fp32 -> bf16 (+ inputs into concat buffer) ---------
// blocks of 2048 elems: mems 384 | Wq 128 | Wc 128 | Wout 256 | inputs 192
// cum: 384, 512, 640, 896, 1088
__global__ __launch_bounds__(256) void prep_cvt(
    const float* __restrict__ inputs, const float* __restrict__ mems,
    const float* __restrict__ Wq, const float* __restrict__ Wc,
    const float* __restrict__ Wout,
    unsigned short* __restrict__ mems_bf, unsigned short* __restrict__ Wq_bf,
    unsigned short* __restrict__ Wc_bf, unsigned short* __restrict__ Wout_bf,
    unsigned short* __restrict__ cat_bf)   // [768][1024], cols 512.. <- inputs
{
    int bid = blockIdx.x;
    const float* s; unsigned short* d; int base; int remap = 0;
    if (bid < 384)      { s = mems;   d = mems_bf; base = bid * 2048; }
    else if (bid < 512) { s = Wq;     d = Wq_bf;   base = (bid - 384) * 2048; }
    else if (bid < 640) { s = Wc;     d = Wc_bf;   base = (bid - 512) * 2048; }
    else if (bid < 896) { s = Wout;   d = Wout_bf; base = (bid - 640) * 2048; }
    else                { s = inputs; d = cat_bf;  base = (bid - 896) * 2048; remap = 1; }
    int idx = base + threadIdx.x * 8;
    float4 a = *(const float4*)(s + idx);
    float4 b = *(const float4*)(s + idx + 4);
    short8 o;
    o[0] = (short)f2bf(a.x); o[1] = (short)f2bf(a.y);
    o[2] = (short)f2bf(a.z); o[3] = (short)f2bf(a.w);
    o[4] = (short)f2bf(b.x); o[5] = (short)f2bf(b.y);
    o[6] = (short)f2bf(b.z); o[7] = (short)f2bf(b.w);
    int dst = remap ? ((idx >> 9) * 1024 + 512 + (idx & 511)) : idx;
    *(short8*)(d + dst) = o;
}

// ---------------- barrier-free per-wave 32x32 MFMA GEMM --------------------
// out[m][n] = bias[n] + sum_k A[m][k]*W[n][k]; A row-major stride LDA, W stride K.
template<int K, int LDA>
__device__ __forceinline__ void wave_gemm(
    const unsigned short* __restrict__ A,
    const unsigned short* __restrict__ W,
    const float* __restrict__ bias,
    float* __restrict__ outF, unsigned short* __restrict__ outB,
    int m0, int n0, int N, int lane)
{
    const int mrow = lane & 15, quad = lane >> 4;
    const unsigned short* ap0 = A + (size_t)(m0 + mrow) * LDA + quad * 8;
    const unsigned short* ap1 = ap0 + 16 * LDA;
    const unsigned short* bp0 = W + (size_t)(n0 + mrow) * K + quad * 8;
    const unsigned short* bp1 = bp0 + 16 * K;

    f32x4 c00 = {0,0,0,0}, c01 = {0,0,0,0}, c10 = {0,0,0,0}, c11 = {0,0,0,0};
    #pragma unroll 4
    for (int ks = 0; ks < K / 32; ++ks) {
        short8 a0 = *(const short8*)(ap0 + ks * 32);
        short8 a1 = *(const short8*)(ap1 + ks * 32);
        short8 b0 = *(const short8*)(bp0 + ks * 32);
        short8 b1 = *(const short8*)(bp1 + ks * 32);
        c00 = __builtin_amdgcn_mfma_f32_16x16x32_bf16(a0, b0, c00, 0, 0, 0);
        c01 = __builtin_amdgcn_mfma_f32_16x16x32_bf16(a0, b1, c01, 0, 0, 0);
        c10 = __builtin_amdgcn_mfma_f32_16x16x32_bf16(a1, b0, c10, 0, 0, 0);
        c11 = __builtin_amdgcn_mfma_f32_16x16x32_bf16(a1, b1, c11, 0, 0, 0);
    }

    f32x4 accs[2][2] = {{c00, c01}, {c10, c11}};
    #pragma unroll
    for (int mi = 0; mi < 2; ++mi) {
        #pragma unroll
        for (int ni = 0; ni < 2; ++ni) {
            int col = n0 + ni * 16 + mrow;
            float bv = bias ? bias[col] : 0.0f;
            #pragma unroll
            for (int rg = 0; rg < 4; ++rg) {
                int row = m0 + mi * 16 + quad * 4 + rg;   // C/D: col=lane&15, row=quad*4+rg
                float val = accs[mi][ni][rg] + bv;
                if (outF) outF[(size_t)row * N + col] = val;
                else      outB[(size_t)row * N + col] = f2bf(val);
            }
        }
    }
}

// fused wq + uh projection. waves: [0,384) wq (24x16 tiles), [384,1152) uh (48x16)
__global__ __launch_bounds__(256) void proj_gemm(
    const unsigned short* __restrict__ cat_bf,   // inputs at cols 512.., LDA 1024
    const unsigned short* __restrict__ mems_bf,
    const unsigned short* __restrict__ Wq_bf,
    const unsigned short* __restrict__ Wc_bf,
    const float* __restrict__ bc,
    unsigned short* __restrict__ wq_o, unsigned short* __restrict__ uh_o)
{
    const int lane = threadIdx.x & 63;
    int gid = blockIdx.x * 4 + (threadIdx.x >> 6);
    if (gid < 384) {
        int wm = gid % 24, wn = gid / 24;
        wave_gemm<DIN, 1024>(cat_bf + 512, Wq_bf, nullptr, nullptr, wq_o,
                             wm * 32, wn * 32, DM, lane);
    } else {
        int g = gid - 384;
        int wm = g % 48, wn = g / 48;
        wave_gemm<DM, DM>(mems_bf, Wc_bf, bc, nullptr, uh_o,
                          wm * 32, wn * 32, DM, lane);
    }
}

// attn_h = cat([c, inputs]) @ Wout^T + bout ; waves 24x16
__global__ __launch_bounds__(256) void out_gemm(
    const unsigned short* __restrict__ cat_bf,
    const unsigned short* __restrict__ Wout_bf,
    const float* __restrict__ bout,
    float* __restrict__ attn_h)
{
    const int lane = threadIdx.x & 63;
    int gid = blockIdx.x * 4 + (threadIdx.x >> 6);
    int wm = gid % 24, wn = gid / 24;
    wave_gemm<1024, 1024>(cat_bf, Wout_bf, bout, attn_h, nullptr,
                          wm * 32, wn * 32, DIN, lane);
}

// ---------------- fused scores + softmax + context, 1 row/block ------------
__global__ __launch_bounds__(256) void attn_core(
    const unsigned short* __restrict__ wq,      // [768][512] bf16
    const unsigned short* __restrict__ uh,      // [1536][512] bf16
    const float* __restrict__ v,                // [512] fp32
    const unsigned short* __restrict__ mems_bf, // [1536][512] bf16
    const int* __restrict__ masks,              // [B]
    float* __restrict__ align_out,              // [768][192] fp32
    unsigned short* __restrict__ cat_bf)        // [768][1024], cols 0..511 <- c
{
    __shared__ float s_al[SS];
    __shared__ float s_inv_sh;
    const int row = blockIdx.x, b = row / TT;
    const int tid = threadIdx.x, lane = tid & 63, w = tid >> 6;
    const int len = masks[b];
    const int mgrp = lane & 15, ssub = lane >> 4;

    // per-lane q,v slices: m = inner*128 + mgrp*8 + j
    float qv[4][8], vv[4][8];
    #pragma unroll
    for (int inner = 0; inner < 4; ++inner) {
        short8 q8 = *(const short8*)(wq + (size_t)row * DM + inner * 128 + mgrp * 8);
        float4 va = *(const float4*)(v + inner * 128 + mgrp * 8);
        float4 vb = *(const float4*)(v + inner * 128 + mgrp * 8 + 4);
        #pragma unroll
        for (int j = 0; j < 8; ++j) qv[inner][j] = bf2f((unsigned short)q8[j]);
        vv[inner][0] = va.x; vv[inner][1] = va.y; vv[inner][2] = va.z; vv[inner][3] = va.w;
        vv[inner][4] = vb.x; vv[inner][5] = vb.y; vv[inner][6] = vb.z; vv[inner][7] = vb.w;
    }

    // scores: wave w covers s in [w*48, w*48+48), 4 s per iter (ssub)
    for (int it = 0; it < 12; ++it) {
        const int s = w * 48 + it * 4 + ssub;
        const unsigned short* up = uh + ((size_t)b * SS + s) * DM + mgrp * 8;
        short8 u[4];
        #pragma unroll
        for (int inner = 0; inner < 4; ++inner)
            u[inner] = *(const short8*)(up + inner * 128);
        float acc = 0.f;
        #pragma unroll
        for (int inner = 0; inner < 4; ++inner)
            #pragma unroll
            for (int j = 0; j < 8; ++j) {
                float x = (qv[inner][j] + bf2f((unsigned short)u[inner][j])) * 2.885390082f;
                float e = __builtin_amdgcn_exp2f(x);
                float t = fmaf(-2.f, __builtin_amdgcn_rcpf(e + 1.f), 1.f);
                acc = fmaf(vv[inner][j], t, acc);
            }
        acc += __shfl_xor(acc, 1);
        acc += __shfl_xor(acc, 2);
        acc += __shfl_xor(acc, 4);
        acc += __shfl_xor(acc, 8);
        if (mgrp == 0) s_al[s] = (s < len) ? acc : -INFINITY;
    }
    __syncthreads();

    // softmax (wave 0)
    if (tid < 64) {
        float m = fmaxf(fmaxf(s_al[tid], s_al[tid + 64]), s_al[tid + 128]);
        #pragma unroll
        for (int off = 32; off; off >>= 1) m = fmaxf(m, __shfl_xor(m, off));
        float e0 = __builtin_amdgcn_exp2f((s_al[tid]       - m) * 1.44269504f);
        float e1 = __builtin_amdgcn_exp2f((s_al[tid + 64]  - m) * 1.44269504f);
        float e2 = __builtin_amdgcn_exp2f((s_al[tid + 128] - m) * 1.44269504f);
        s_al[tid] = e0; s_al[tid + 64] = e1; s_al[tid + 128] = e2;
        float sum = e0 + e1 + e2;
        #pragma unroll
        for (int off = 32; off; off >>= 1) sum += __shfl_xor(sum, off);
        if (tid == 0) s_inv_sh = 1.0f / sum;
    }
    __syncthreads();
    const float inv = s_inv_sh;
    if (tid < SS) align_out[(size_t)row * SS + tid] = s_al[tid] * inv;

    // context: thread owns dims {2*tid, 2*tid+1}; masked s contribute P=0
    const unsigned short* mb = mems_bf + (size_t)b * SS * DM + tid * 2;
    float a0 = 0.f, a1 = 0.f;
    #pragma unroll 8
    for (int s = 0; s < SS; ++s) {
        unsigned int uu = *(const unsigned int*)(mb + (size_t)s * DM);
        float p = s_al[s];
        a0 = fmaf(p, __uint_as_float(uu << 16), a0);
        a1 = fmaf(p, __uint_as_float(uu & 0xFFFF0000u), a1);
    }
    unsigned int pack = ((unsigned int)f2bf(a1 * inv) << 16) | (unsigned int)f2bf(a0 * inv);
    *(unsigned int*)(cat_bf + (size_t)row * 1024 + tid * 2) = pack;
}

extern "C" void kernel_launch(void* const* d_in, const int* in_sizes, int n_in,
                              void* d_out, int out_size, void* d_ws, size_t ws_size,
                              hipStream_t stream) {
    (void)in_sizes; (void)n_in; (void)out_size; (void)ws_size;
    const float* inputs = (const float*)d_in[0];
    const float* mems   = (const float*)d_in[1];
    const int*   masks  = (const int*)  d_in[2];
    const float* Wq     = (const float*)d_in[3];
    const float* Wc     = (const float*)d_in[4];
    const float* bc     = (const float*)d_in[5];
    const float* v      = (const float*)d_in[6];
    const float* Wout   = (const float*)d_in[7];
    const float* bout   = (const float*)d_in[8];

    unsigned short* p = (unsigned short*)d_ws;
    unsigned short* mems_bf = p;  p += 786432;   // [1536][512]
    unsigned short* Wq_bf   = p;  p += 262144;   // [512][512]
    unsigned short* Wc_bf   = p;  p += 262144;   // [512][512]
    unsigned short* Wout_bf = p;  p += 524288;   // [512][1024]
    unsigned short* wq_bf   = p;  p += 393216;   // [768][512]
    unsigned short* uh_bf   = p;  p += 786432;   // [1536][512]
    unsigned short* cat_bf  = p;  p += 786432;   // [768][1024]

    float* attn_h    = (float*)d_out;                    // [768][512]
    float* align_out = attn_h + (size_t)BB * TT * DIN;   // [768][192]

    prep_cvt<<<1088, 256, 0, stream>>>(inputs, mems, Wq, Wc, Wout,
                                       mems_bf, Wq_bf, Wc_bf, Wout_bf, cat_bf);
    proj_gemm<<<288, 256, 0, stream>>>(cat_bf, mems_bf, Wq_bf, Wc_bf, bc,
                                       wq_bf, uh_bf);
    attn_core<<<BB * TT, 256, 0, stream>>>(wq_bf, uh_bf, v, mems_bf, masks,
                                           align_out, cat_bf);
    out_gemm<<<96, 256, 0, stream>>>(cat_bf, Wout_bf, bout, attn_h);
}

// Round 5
// 134.863 us; speedup vs baseline: 1.1030x; 1.0774x over previous
//
#include <hip/hip_runtime.h>
#include <math.h>

#define BB 8
#define TT 96
#define SS 192
#define DIN 512
#define DM 512

typedef short short8 __attribute__((ext_vector_type(8)));
typedef float f32x4 __attribute__((ext_vector_type(4)));

__device__ __forceinline__ unsigned short f2bf(float f) {
    unsigned int u = __float_as_uint(f);
    unsigned int r = u + 0x7FFFu + ((u >> 16) & 1u);   // RNE
    return (unsigned short)(r >> 16);
}
__device__ __forceinline__ float bf2f(unsigned short h) {
    return __uint_as_float(((unsigned int)h) << 16);
}

// ---------------- prep: fp32 -> bf16 (+ inputs into concat buffer) ---------
// blocks of 2048 elems: mems 384 | Wq 128 | Wc 128 | Wout 256 | inputs 192
__global__ __launch_bounds__(256) void prep_cvt(
    const float* __restrict__ inputs, const float* __restrict__ mems,
    const float* __restrict__ Wq, const float* __restrict__ Wc,
    const float* __restrict__ Wout,
    unsigned short* __restrict__ mems_bf, unsigned short* __restrict__ Wq_bf,
    unsigned short* __restrict__ Wc_bf, unsigned short* __restrict__ Wout_bf,
    unsigned short* __restrict__ cat_bf)   // [768][1024], cols 512.. <- inputs
{
    int bid = blockIdx.x;
    const float* s; unsigned short* d; int base; int remap = 0;
    if (bid < 384)      { s = mems;   d = mems_bf; base = bid * 2048; }
    else if (bid < 512) { s = Wq;     d = Wq_bf;   base = (bid - 384) * 2048; }
    else if (bid < 640) { s = Wc;     d = Wc_bf;   base = (bid - 512) * 2048; }
    else if (bid < 896) { s = Wout;   d = Wout_bf; base = (bid - 640) * 2048; }
    else                { s = inputs; d = cat_bf;  base = (bid - 896) * 2048; remap = 1; }
    int idx = base + threadIdx.x * 8;
    float4 a = *(const float4*)(s + idx);
    float4 b = *(const float4*)(s + idx + 4);
    short8 o;
    o[0] = (short)f2bf(a.x); o[1] = (short)f2bf(a.y);
    o[2] = (short)f2bf(a.z); o[3] = (short)f2bf(a.w);
    o[4] = (short)f2bf(b.x); o[5] = (short)f2bf(b.y);
    o[6] = (short)f2bf(b.z); o[7] = (short)f2bf(b.w);
    int dst = remap ? ((idx >> 9) * 1024 + 512 + (idx & 511)) : idx;
    *(short8*)(d + dst) = o;
}

// ---------------- pipelined barrier-free per-wave MFMA GEMMs ---------------
// 32x32 tile: register double-buffer; loads for iter k+1 in flight during
// MFMAs of iter k (latency tolerance at ~1 wave/SIMD).
template<int K, int LDA>
__device__ __forceinline__ void wave_gemm32(
    const unsigned short* __restrict__ A,
    const unsigned short* __restrict__ W,
    const float* __restrict__ bias,
    float* __restrict__ outF, unsigned short* __restrict__ outB,
    int m0, int n0, int N, int lane)
{
    const int mrow = lane & 15, quad = lane >> 4;
    const unsigned short* ap0 = A + (size_t)(m0 + mrow) * LDA + quad * 8;
    const unsigned short* ap1 = ap0 + 16 * (size_t)LDA;
    const unsigned short* bp0 = W + (size_t)(n0 + mrow) * K + quad * 8;
    const unsigned short* bp1 = bp0 + 16 * (size_t)K;

    f32x4 c00 = {0,0,0,0}, c01 = {0,0,0,0}, c10 = {0,0,0,0}, c11 = {0,0,0,0};
    short8 a0 = *(const short8*)ap0, a1 = *(const short8*)ap1;
    short8 b0 = *(const short8*)bp0, b1 = *(const short8*)bp1;

    #pragma unroll
    for (int ks = 0; ks < K / 32; ++ks) {
        short8 na0 = a0, na1 = a1, nb0 = b0, nb1 = b1;
        if (ks + 1 < K / 32) {
            na0 = *(const short8*)(ap0 + (ks + 1) * 32);
            na1 = *(const short8*)(ap1 + (ks + 1) * 32);
            nb0 = *(const short8*)(bp0 + (ks + 1) * 32);
            nb1 = *(const short8*)(bp1 + (ks + 1) * 32);
        }
        c00 = __builtin_amdgcn_mfma_f32_16x16x32_bf16(a0, b0, c00, 0, 0, 0);
        c01 = __builtin_amdgcn_mfma_f32_16x16x32_bf16(a0, b1, c01, 0, 0, 0);
        c10 = __builtin_amdgcn_mfma_f32_16x16x32_bf16(a1, b0, c10, 0, 0, 0);
        c11 = __builtin_amdgcn_mfma_f32_16x16x32_bf16(a1, b1, c11, 0, 0, 0);
        a0 = na0; a1 = na1; b0 = nb0; b1 = nb1;
    }

    f32x4 accs[2][2] = {{c00, c01}, {c10, c11}};
    #pragma unroll
    for (int mi = 0; mi < 2; ++mi)
        #pragma unroll
        for (int ni = 0; ni < 2; ++ni) {
            int col = n0 + ni * 16 + mrow;
            float bv = bias ? bias[col] : 0.0f;
            #pragma unroll
            for (int rg = 0; rg < 4; ++rg) {
                int row = m0 + mi * 16 + quad * 4 + rg;   // col=lane&15, row=quad*4+rg
                float val = accs[mi][ni][rg] + bv;
                if (outF) outF[(size_t)row * N + col] = val;
                else      outB[(size_t)row * N + col] = f2bf(val);
            }
        }
}

// 16x32 tile variant (more waves for small-M GEMMs)
template<int K, int LDA>
__device__ __forceinline__ void wave_gemm16(
    const unsigned short* __restrict__ A,
    const unsigned short* __restrict__ W,
    const float* __restrict__ bias,
    float* __restrict__ outF,
    int m0, int n0, int N, int lane)
{
    const int mrow = lane & 15, quad = lane >> 4;
    const unsigned short* ap0 = A + (size_t)(m0 + mrow) * LDA + quad * 8;
    const unsigned short* bp0 = W + (size_t)(n0 + mrow) * K + quad * 8;
    const unsigned short* bp1 = bp0 + 16 * (size_t)K;

    f32x4 c0 = {0,0,0,0}, c1 = {0,0,0,0};
    short8 a0 = *(const short8*)ap0;
    short8 b0 = *(const short8*)bp0, b1 = *(const short8*)bp1;

    #pragma unroll 8
    for (int ks = 0; ks < K / 32; ++ks) {
        short8 na0 = a0, nb0 = b0, nb1 = b1;
        if (ks + 1 < K / 32) {
            na0 = *(const short8*)(ap0 + (ks + 1) * 32);
            nb0 = *(const short8*)(bp0 + (ks + 1) * 32);
            nb1 = *(const short8*)(bp1 + (ks + 1) * 32);
        }
        c0 = __builtin_amdgcn_mfma_f32_16x16x32_bf16(a0, b0, c0, 0, 0, 0);
        c1 = __builtin_amdgcn_mfma_f32_16x16x32_bf16(a0, b1, c1, 0, 0, 0);
        a0 = na0; b0 = nb0; b1 = nb1;
    }

    f32x4 accs[2] = {c0, c1};
    #pragma unroll
    for (int ni = 0; ni < 2; ++ni) {
        int col = n0 + ni * 16 + mrow;
        float bv = bias ? bias[col] : 0.0f;
        #pragma unroll
        for (int rg = 0; rg < 4; ++rg) {
            int row = m0 + quad * 4 + rg;
            outF[(size_t)row * N + col] = accs[ni][rg] + bv;
        }
    }
}

// fused wq + uh projection. waves: [0,384) wq (24x16 tiles), [384,1152) uh (48x16)
__global__ __launch_bounds__(256) void proj_gemm(
    const unsigned short* __restrict__ cat_bf,
    const unsigned short* __restrict__ mems_bf,
    const unsigned short* __restrict__ Wq_bf,
    const unsigned short* __restrict__ Wc_bf,
    const float* __restrict__ bc,
    unsigned short* __restrict__ wq_o, unsigned short* __restrict__ uh_o)
{
    const int lane = threadIdx.x & 63;
    int gid = blockIdx.x * 4 + (threadIdx.x >> 6);
    if (gid < 384) {
        int wm = gid % 24, wn = gid / 24;
        wave_gemm32<DIN, 1024>(cat_bf + 512, Wq_bf, nullptr, nullptr, wq_o,
                               wm * 32, wn * 32, DM, lane);
    } else {
        int g = gid - 384;
        int wm = g % 48, wn = g / 48;
        wave_gemm32<DM, DM>(mems_bf, Wc_bf, bc, nullptr, uh_o,
                            wm * 32, wn * 32, DM, lane);
    }
}

// attn_h = cat([c, inputs]) @ Wout^T + bout ; 768 waves of 16x32 tiles
__global__ __launch_bounds__(256) void out_gemm(
    const unsigned short* __restrict__ cat_bf,
    const unsigned short* __restrict__ Wout_bf,
    const float* __restrict__ bout,
    float* __restrict__ attn_h)
{
    const int lane = threadIdx.x & 63;
    int gid = blockIdx.x * 4 + (threadIdx.x >> 6);   // [0,768)
    int wm = gid % 48, wn = gid / 48;
    wave_gemm16<1024, 1024>(cat_bf, Wout_bf, bout, attn_h,
                            wm * 16, wn * 32, DIN, lane);
}

// ---------------- fused scores + softmax + context, 1 row/block ------------
__global__ __launch_bounds__(256) void attn_core(
    const unsigned short* __restrict__ wq,      // [768][512] bf16
    const unsigned short* __restrict__ uh,      // [1536][512] bf16
    const float* __restrict__ v,                // [512] fp32
    const unsigned short* __restrict__ mems_bf, // [1536][512] bf16
    const int* __restrict__ masks,              // [B]
    float* __restrict__ align_out,              // [768][192] fp32
    unsigned short* __restrict__ cat_bf)        // [768][1024], cols 0..511 <- c
{
    __shared__ float s_al[SS];
    __shared__ float s_part[4][DM];
    __shared__ float s_inv_sh;
    const int row = blockIdx.x, b = row / TT;
    const int tid = threadIdx.x, lane = tid & 63, w = tid >> 6;
    const int len = masks[b];
    const int mgrp = lane & 15, ssub = lane >> 4;

    // per-lane q,v slices: m = inner*128 + mgrp*8 + j
    float qv[4][8], vv[4][8];
    #pragma unroll
    for (int inner = 0; inner < 4; ++inner) {
        short8 q8 = *(const short8*)(wq + (size_t)row * DM + inner * 128 + mgrp * 8);
        float4 va = *(const float4*)(v + inner * 128 + mgrp * 8);
        float4 vb = *(const float4*)(v + inner * 128 + mgrp * 8 + 4);
        #pragma unroll
        for (int j = 0; j < 8; ++j) qv[inner][j] = bf2f((unsigned short)q8[j]);
        vv[inner][0] = va.x; vv[inner][1] = va.y; vv[inner][2] = va.z; vv[inner][3] = va.w;
        vv[inner][4] = vb.x; vv[inner][5] = vb.y; vv[inner][6] = vb.z; vv[inner][7] = vb.w;
    }

    // scores: wave w covers s in [w*48, w*48+48), 4 s per iter (ssub)
    for (int it = 0; it < 12; ++it) {
        const int s = w * 48 + it * 4 + ssub;
        const unsigned short* up = uh + ((size_t)b * SS + s) * DM + mgrp * 8;
        short8 u[4];
        #pragma unroll
        for (int inner = 0; inner < 4; ++inner)
            u[inner] = *(const short8*)(up + inner * 128);
        float acc = 0.f;
        #pragma unroll
        for (int inner = 0; inner < 4; ++inner)
            #pragma unroll
            for (int j = 0; j < 8; ++j) {
                float x = (qv[inner][j] + bf2f((unsigned short)u[inner][j])) * 2.885390082f;
                float e = __builtin_amdgcn_exp2f(x);
                float t = fmaf(-2.f, __builtin_amdgcn_rcpf(e + 1.f), 1.f);
                acc = fmaf(vv[inner][j], t, acc);
            }
        acc += __shfl_xor(acc, 1);
        acc += __shfl_xor(acc, 2);
        acc += __shfl_xor(acc, 4);
        acc += __shfl_xor(acc, 8);
        if (mgrp == 0) s_al[s] = (s < len) ? acc : -INFINITY;
    }
    __syncthreads();

    // softmax (wave 0)
    if (tid < 64) {
        float m = fmaxf(fmaxf(s_al[tid], s_al[tid + 64]), s_al[tid + 128]);
        #pragma unroll
        for (int off = 32; off; off >>= 1) m = fmaxf(m, __shfl_xor(m, off));
        float e0 = __builtin_amdgcn_exp2f((s_al[tid]       - m) * 1.44269504f);
        float e1 = __builtin_amdgcn_exp2f((s_al[tid + 64]  - m) * 1.44269504f);
        float e2 = __builtin_amdgcn_exp2f((s_al[tid + 128] - m) * 1.44269504f);
        s_al[tid] = e0; s_al[tid + 64] = e1; s_al[tid + 128] = e2;
        float sum = e0 + e1 + e2;
        #pragma unroll
        for (int off = 32; off; off >>= 1) sum += __shfl_xor(sum, off);
        if (tid == 0) s_inv_sh = 1.0f / sum;
    }
    __syncthreads();
    const float inv = s_inv_sh;
    if (tid < SS) align_out[(size_t)row * SS + tid] = s_al[tid] * inv;

    // context: wave w accumulates s in [w*48,w*48+48), lane owns d=lane*8..+8
    float ac[8] = {0,0,0,0,0,0,0,0};
    {
        const unsigned short* mb = mems_bf + ((size_t)b * SS + w * 48) * DM + lane * 8;
        #pragma unroll 6
        for (int i = 0; i < 48; ++i) {
            short8 mv = *(const short8*)(mb + (size_t)i * DM);
            float p = s_al[w * 48 + i];
            #pragma unroll
            for (int j = 0; j < 8; ++j)
                ac[j] = fmaf(p, bf2f((unsigned short)mv[j]), ac[j]);
        }
        #pragma unroll
        for (int j = 0; j < 8; ++j) s_part[w][lane * 8 + j] = ac[j];
    }
    __syncthreads();

    // reduce partials: thread owns d = {2*tid, 2*tid+1}
    const int d = tid * 2;
    float r0 = s_part[0][d]     + s_part[1][d]     + s_part[2][d]     + s_part[3][d];
    float r1 = s_part[0][d + 1] + s_part[1][d + 1] + s_part[2][d + 1] + s_part[3][d + 1];
    unsigned int pack = ((unsigned int)f2bf(r1 * inv) << 16) | (unsigned int)f2bf(r0 * inv);
    *(unsigned int*)(cat_bf + (size_t)row * 1024 + d) = pack;
}

extern "C" void kernel_launch(void* const* d_in, const int* in_sizes, int n_in,
                              void* d_out, int out_size, void* d_ws, size_t ws_size,
                              hipStream_t stream) {
    (void)in_sizes; (void)n_in; (void)out_size; (void)ws_size;
    const float* inputs = (const float*)d_in[0];
    const float* mems   = (const float*)d_in[1];
    const int*   masks  = (const int*)  d_in[2];
    const float* Wq     = (const float*)d_in[3];
    const float* Wc     = (const float*)d_in[4];
    const float* bc     = (const float*)d_in[5];
    const float* v      = (const float*)d_in[6];
    const float* Wout   = (const float*)d_in[7];
    const float* bout   = (const float*)d_in[8];

    unsigned short* p = (unsigned short*)d_ws;
    unsigned short* mems_bf = p;  p += 786432;   // [1536][512]
    unsigned short* Wq_bf   = p;  p += 262144;   // [512][512]
    unsigned short* Wc_bf   = p;  p += 262144;   // [512][512]
    unsigned short* Wout_bf = p;  p += 524288;   // [512][1024]
    unsigned short* wq_bf   = p;  p += 393216;   // [768][512]
    unsigned short* uh_bf   = p;  p += 786432;   // [1536][512]
    unsigned short* cat_bf  = p;  p += 786432;   // [768][1024]

    float* attn_h    = (float*)d_out;                    // [768][512]
    float* align_out = attn_h + (size_t)BB * TT * DIN;   // [768][192]

    prep_cvt<<<1088, 256, 0, stream>>>(inputs, mems, Wq, Wc, Wout,
                                       mems_bf, Wq_bf, Wc_bf, Wout_bf, cat_bf);
    proj_gemm<<<288, 256, 0, stream>>>(cat_bf, mems_bf, Wq_bf, Wc_bf, bc,
                                       wq_bf, uh_bf);
    attn_core<<<BB * TT, 256, 0, stream>>>(wq_bf, uh_bf, v, mems_bf, masks,
                                           align_out, cat_bf);
    out_gemm<<<192, 256, 0, stream>>>(cat_bf, Wout_bf, bout, attn_h);
}